// Round 1
// baseline (1052.866 us; speedup 1.0000x reference)
//
#include <hip/hip_runtime.h>
#include <hip/hip_bf16.h>

// Problem constants (RoutedExperts: N=16384, D=2048, H=1024, E=16)
#define NE 16
#define NT 1024   // tokens per expert
#define ND 2048   // model dim
#define NH 1024   // hidden dim

typedef __bf16 bf16x8 __attribute__((ext_vector_type(8)));
typedef __bf16 bf16x4 __attribute__((ext_vector_type(4)));
typedef float  f32x4  __attribute__((ext_vector_type(4)));

constexpr int BM = 128, BN = 128, BK = 32;
constexpr int LDSS = 40;  // padded LDS row stride (bf16 elems): 80B, 16B-aligned, 2-way max on b128

// ---------------------------------------------------------------------------
// NT GEMM: C[m][n] = sum_k A[m][k] * B[n][k], per-expert batch in blockIdx.z.
// Both A and B are row-major with K contiguous (lda = ldb = K). ldc = 2048.
// AF32/BF32: operand is fp32 (convert to bf16 during staging), else bf16.
// CBF16: write bf16, else fp32.
// ---------------------------------------------------------------------------
template<bool AF32, bool BF32, bool CBF16>
__global__ __launch_bounds__(256, 2)
void gemm_nt(const void* __restrict__ Ap, const void* __restrict__ Bp,
             void* __restrict__ Cp, int K, long sA, long sB, long sC)
{
  __shared__ __bf16 As[BM * LDSS];
  __shared__ __bf16 Bs[BN * LDSS];

  const int tid  = threadIdx.x;
  const int lane = tid & 63;
  const int wave = tid >> 6;
  const int wr = wave >> 1, wc = wave & 1;   // 2x2 waves, each 64x64
  const int m0 = blockIdx.y * BM;
  const int n0 = blockIdx.x * BN;
  const long zb = blockIdx.z;

  f32x4 acc[4][4] = {};

  const int kq  = (lane >> 4) * 8;  // k-chunk per lane-quad (A/B frag: k = quad*8 + j)
  const int l15 = lane & 15;

  for (int kk = 0; kk < K; kk += BK) {
    // ---- stage A tile (BM x BK) ----
    if constexpr (AF32) {
      const float* A = (const float*)Ap + zb * sA + (long)m0 * K + kk;
      #pragma unroll
      for (int p = 0; p < 4; ++p) {
        const int r = p * 32 + (tid >> 3);
        const int c = (tid & 7) * 4;
        const float4 v = *(const float4*)(A + (long)r * K + c);
        bf16x4 w;
        w[0] = (__bf16)v.x; w[1] = (__bf16)v.y; w[2] = (__bf16)v.z; w[3] = (__bf16)v.w;
        *(bf16x4*)(&As[r * LDSS + c]) = w;
      }
    } else {
      const __bf16* A = (const __bf16*)Ap + zb * sA + (long)m0 * K + kk;
      #pragma unroll
      for (int p = 0; p < 2; ++p) {
        const int r = p * 64 + (tid >> 2);
        const int c = (tid & 3) * 8;
        *(bf16x8*)(&As[r * LDSS + c]) = *(const bf16x8*)(A + (long)r * K + c);
      }
    }
    // ---- stage B tile (BN x BK) ----
    if constexpr (BF32) {
      const float* B = (const float*)Bp + zb * sB + (long)n0 * K + kk;
      #pragma unroll
      for (int p = 0; p < 4; ++p) {
        const int r = p * 32 + (tid >> 3);
        const int c = (tid & 7) * 4;
        const float4 v = *(const float4*)(B + (long)r * K + c);
        bf16x4 w;
        w[0] = (__bf16)v.x; w[1] = (__bf16)v.y; w[2] = (__bf16)v.z; w[3] = (__bf16)v.w;
        *(bf16x4*)(&Bs[r * LDSS + c]) = w;
      }
    } else {
      const __bf16* B = (const __bf16*)Bp + zb * sB + (long)n0 * K + kk;
      #pragma unroll
      for (int p = 0; p < 2; ++p) {
        const int r = p * 64 + (tid >> 2);
        const int c = (tid & 3) * 8;
        *(bf16x8*)(&Bs[r * LDSS + c]) = *(const bf16x8*)(B + (long)r * K + c);
      }
    }
    __syncthreads();

    // ---- fragments + MFMA ----
    bf16x8 af[4], bq[4];
    #pragma unroll
    for (int i = 0; i < 4; ++i)
      af[i] = *(const bf16x8*)(&As[(wr * 64 + i * 16 + l15) * LDSS + kq]);
    #pragma unroll
    for (int j = 0; j < 4; ++j)
      bq[j] = *(const bf16x8*)(&Bs[(wc * 64 + j * 16 + l15) * LDSS + kq]);
    #pragma unroll
    for (int i = 0; i < 4; ++i)
      #pragma unroll
      for (int j = 0; j < 4; ++j)
        acc[i][j] = __builtin_amdgcn_mfma_f32_16x16x32_bf16(af[i], bq[j], acc[i][j], 0, 0, 0);
    __syncthreads();
  }

  // ---- epilogue: C/D layout col = lane&15, row = (lane>>4)*4 + reg ----
  const int rq = (lane >> 4) * 4;
  if constexpr (CBF16) {
    __bf16* C = (__bf16*)Cp + zb * sC;
    #pragma unroll
    for (int i = 0; i < 4; ++i)
      #pragma unroll
      for (int j = 0; j < 4; ++j)
        #pragma unroll
        for (int r = 0; r < 4; ++r)
          C[(long)(m0 + wr * 64 + i * 16 + rq + r) * 2048 +
            (n0 + wc * 64 + j * 16 + l15)] = (__bf16)acc[i][j][r];
  } else {
    float* C = (float*)Cp + zb * sC;
    #pragma unroll
    for (int i = 0; i < 4; ++i)
      #pragma unroll
      for (int j = 0; j < 4; ++j)
        #pragma unroll
        for (int r = 0; r < 4; ++r)
          C[(long)(m0 + wr * 64 + i * 16 + rq + r) * 2048 +
            (n0 + wc * 64 + j * 16 + l15)] = acc[i][j][r];
  }
}

// ---------------------------------------------------------------------------
// w_down (E,H,D) fp32  ->  wdT (E,D,H) bf16   (64x64 tiles via LDS)
// ---------------------------------------------------------------------------
__global__ __launch_bounds__(256)
void transpose_cast_wdown(const float* __restrict__ w, __bf16* __restrict__ wt)
{
  __shared__ __bf16 lt[64][72];  // 72: 16B-aligned rows
  const int e  = blockIdx.z;
  const int hb = blockIdx.y * 64;
  const int db = blockIdx.x * 64;
  const int tid = threadIdx.x;
  const int r  = tid >> 2;         // 0..63
  const int cq = (tid & 3) * 16;   // column chunk

  const float* src = w + (long)e * NH * ND + (long)(hb + r) * ND + db + cq;
  #pragma unroll
  for (int q = 0; q < 4; ++q) {
    const float4 v = *(const float4*)(src + q * 4);
    lt[cq + q * 4 + 0][r] = (__bf16)v.x;
    lt[cq + q * 4 + 1][r] = (__bf16)v.y;
    lt[cq + q * 4 + 2][r] = (__bf16)v.z;
    lt[cq + q * 4 + 3][r] = (__bf16)v.w;
  }
  __syncthreads();
  __bf16* dst = wt + (long)e * ND * NH + (long)(db + r) * NH + hb + cq;
  *(bf16x8*)(dst)     = *(const bf16x8*)(&lt[r][cq]);
  *(bf16x8*)(dst + 8) = *(const bf16x8*)(&lt[r][cq + 8]);
}

// ---------------------------------------------------------------------------
// h[row][c] = up[row][c] * silu(gate[row][c]);  ug is (E*T, 2H), h is (E*T, H)
// ---------------------------------------------------------------------------
__global__ __launch_bounds__(256)
void silu_mul(const __bf16* __restrict__ ug, __bf16* __restrict__ h)
{
  const long g  = (long)blockIdx.x * 256 + threadIdx.x;  // [0, 16384*128)
  const int  c8 = (int)(g & 127) * 8;
  const long row = g >> 7;
  const bf16x8 u  = *(const bf16x8*)(ug + row * 2048 + c8);
  const bf16x8 gt = *(const bf16x8*)(ug + row * 2048 + 1024 + c8);
  bf16x8 o;
  #pragma unroll
  for (int i = 0; i < 8; ++i) {
    const float uu = (float)u[i];
    const float gg = (float)gt[i];
    const float s  = gg / (1.0f + __expf(-gg));
    o[i] = (__bf16)(uu * s);
  }
  *(bf16x8*)(h + row * 1024 + c8) = o;
}

// ---------------------------------------------------------------------------
extern "C" void kernel_launch(void* const* d_in, const int* in_sizes, int n_in,
                              void* d_out, int out_size, void* d_ws, size_t ws_size,
                              hipStream_t stream) {
  const float* x   = (const float*)d_in[0];  // (16384, 2048)
  const float* wug = (const float*)d_in[1];  // (16, 2048, 2048)
  const float* wdn = (const float*)d_in[2];  // (16, 1024, 2048)
  // d_in[3] = batch_size_per_expert — unused by the reference (static routing)
  float* out = (float*)d_out;

  char* ws = (char*)d_ws;
  __bf16* wdT = (__bf16*)ws;                          // E*D*H bf16 = 64 MB
  __bf16* ug  = (__bf16*)(ws + 67108864);             // E*T*2H bf16 = 64 MB
  __bf16* hbf = (__bf16*)(ws + 134217728);            // E*T*H bf16 = 32 MB

  // 1) transpose+cast w_down -> (E, D, H) bf16
  transpose_cast_wdown<<<dim3(ND / 64, NH / 64, NE), 256, 0, stream>>>(wdn, wdT);

  // 2) GEMM1: ug[e][t][n] = sum_d x[e][t][d] * wug[e][n][d]   (n in [0,2H))
  gemm_nt<true, true, true><<<dim3(2 * NH / BN, NT / BM, NE), 256, 0, stream>>>(
      x, wug, ug, ND, (long)NT * ND, (long)2 * NH * ND, (long)NT * 2 * NH);

  // 3) h = up * silu(gate)
  silu_mul<<<(NE * NT * NH / 8) / 256, 256, 0, stream>>>(ug, hbf);

  // 4) GEMM2: out[e][t][d] = sum_h h[e][t][h] * wdT[e][d][h]
  gemm_nt<false, false, false><<<dim3(ND / BN, NT / BM, NE), 256, 0, stream>>>(
      hbf, wdT, out, NH, (long)NT * NH, (long)ND * NH, (long)NT * ND);
}

// Round 2
// 851.521 us; speedup vs baseline: 1.2365x; 1.2365x over previous
//
#include <hip/hip_runtime.h>
#include <hip/hip_bf16.h>

// Problem constants (RoutedExperts: N=16384, D=2048, H=1024, E=16)
#define NE 16
#define NT 1024   // tokens per expert
#define ND 2048   // model dim
#define NH 1024   // hidden dim

typedef __bf16 bf16x8 __attribute__((ext_vector_type(8)));
typedef __bf16 bf16x4 __attribute__((ext_vector_type(4)));
typedef float  f32x4  __attribute__((ext_vector_type(4)));

// ---------------------------------------------------------------------------
// async global->LDS, 16B per lane. LDS dest is wave-uniform base + lane*16.
// ---------------------------------------------------------------------------
__device__ __forceinline__ void async_load16(const __bf16* g, __bf16* l) {
  __builtin_amdgcn_global_load_lds(
      (const __attribute__((address_space(1))) void*)g,
      (__attribute__((address_space(3))) void*)l, 16, 0, 0);
}

// ---------------------------------------------------------------------------
// m97-structure NT GEMM, bf16 inputs: C[m][n] = sum_k A[m][k]*B[n][k].
// 128x128 tile, BK=32, 4 waves in 2x2 of 64x64, 16x16x32 MFMA.
// LDS tiles contiguous (128x32 bf16, no padding — required by global_load_lds).
// ldc = 2048 for both call sites. CBF16: write bf16 else fp32.
// ---------------------------------------------------------------------------
template<bool CBF16>
__global__ __launch_bounds__(256, 2)
void gemm_nt_lds(const __bf16* __restrict__ Ap, const __bf16* __restrict__ Bp,
                 void* __restrict__ Cp, int K, long sA, long sB, long sC)
{
  __shared__ __bf16 As[128 * 32];
  __shared__ __bf16 Bs[128 * 32];

  const int tid  = threadIdx.x;
  const int lane = tid & 63;
  const int wave = tid >> 6;
  const int wr = wave >> 1, wc = wave & 1;
  const int m0 = blockIdx.y * 128;
  const int n0 = blockIdx.x * 128;
  const long zb = blockIdx.z;

  const __bf16* A = Ap + zb * sA + (long)m0 * K;
  const __bf16* B = Bp + zb * sB + (long)n0 * K;

  // staging coords: slab = 16 rows x 32 cols = 1 wave-issue (64 lanes x 16B)
  const int sr = lane >> 2;        // row within slab
  const int sc = (lane & 3) * 8;   // col (8 bf16 = 16B)

  f32x4 acc[4][4] = {};
  const int kq  = (lane >> 4) * 8; // frag k-chunk: k = quad*8 + j
  const int l15 = lane & 15;

  for (int kk = 0; kk < K; kk += 32) {
    #pragma unroll
    for (int p = 0; p < 2; ++p) {
      const int slab = wave * 2 + p;            // 0..7
      const int r = slab * 16 + sr;
      async_load16(A + (long)r * K + kk + sc, &As[slab * 512]);
      async_load16(B + (long)r * K + kk + sc, &Bs[slab * 512]);
    }
    __syncthreads();   // drains vmcnt(0) — global_load_lds complete

    bf16x8 af[4], bq[4];
    #pragma unroll
    for (int i = 0; i < 4; ++i)
      af[i] = *(const bf16x8*)(&As[(wr * 64 + i * 16 + l15) * 32 + kq]);
    #pragma unroll
    for (int j = 0; j < 4; ++j)
      bq[j] = *(const bf16x8*)(&Bs[(wc * 64 + j * 16 + l15) * 32 + kq]);
    #pragma unroll
    for (int i = 0; i < 4; ++i)
      #pragma unroll
      for (int j = 0; j < 4; ++j)
        acc[i][j] = __builtin_amdgcn_mfma_f32_16x16x32_bf16(af[i], bq[j], acc[i][j], 0, 0, 0);
    __syncthreads();
  }

  // epilogue: C/D layout col = lane&15, row = (lane>>4)*4 + reg
  const int rq = (lane >> 4) * 4;
  if constexpr (CBF16) {
    __bf16* C = (__bf16*)Cp + zb * sC;
    #pragma unroll
    for (int i = 0; i < 4; ++i)
      #pragma unroll
      for (int j = 0; j < 4; ++j)
        #pragma unroll
        for (int r = 0; r < 4; ++r)
          C[(long)(m0 + wr * 64 + i * 16 + rq + r) * 2048 +
            (n0 + wc * 64 + j * 16 + l15)] = (__bf16)acc[i][j][r];
  } else {
    float* C = (float*)Cp + zb * sC;
    #pragma unroll
    for (int i = 0; i < 4; ++i)
      #pragma unroll
      for (int j = 0; j < 4; ++j)
        #pragma unroll
        for (int r = 0; r < 4; ++r)
          C[(long)(m0 + wr * 64 + i * 16 + rq + r) * 2048 +
            (n0 + wc * 64 + j * 16 + l15)] = acc[i][j][r];
  }
}

// ---------------------------------------------------------------------------
// Fallback (round-1) NT GEMM with in-kernel fp32->bf16 staging.
// ---------------------------------------------------------------------------
constexpr int LDSS = 40;
template<bool AF32, bool BF32, bool CBF16>
__global__ __launch_bounds__(256, 2)
void gemm_nt(const void* __restrict__ Ap, const void* __restrict__ Bp,
             void* __restrict__ Cp, int K, long sA, long sB, long sC)
{
  __shared__ __bf16 As[128 * LDSS];
  __shared__ __bf16 Bs[128 * LDSS];
  const int tid  = threadIdx.x;
  const int lane = tid & 63;
  const int wave = tid >> 6;
  const int wr = wave >> 1, wc = wave & 1;
  const int m0 = blockIdx.y * 128;
  const int n0 = blockIdx.x * 128;
  const long zb = blockIdx.z;
  f32x4 acc[4][4] = {};
  const int kq  = (lane >> 4) * 8;
  const int l15 = lane & 15;

  for (int kk = 0; kk < K; kk += 32) {
    if constexpr (AF32) {
      const float* A = (const float*)Ap + zb * sA + (long)m0 * K + kk;
      #pragma unroll
      for (int p = 0; p < 4; ++p) {
        const int r = p * 32 + (tid >> 3);
        const int c = (tid & 7) * 4;
        const float4 v = *(const float4*)(A + (long)r * K + c);
        bf16x4 w;
        w[0] = (__bf16)v.x; w[1] = (__bf16)v.y; w[2] = (__bf16)v.z; w[3] = (__bf16)v.w;
        *(bf16x4*)(&As[r * LDSS + c]) = w;
      }
    } else {
      const __bf16* A = (const __bf16*)Ap + zb * sA + (long)m0 * K + kk;
      #pragma unroll
      for (int p = 0; p < 2; ++p) {
        const int r = p * 64 + (tid >> 2);
        const int c = (tid & 3) * 8;
        *(bf16x8*)(&As[r * LDSS + c]) = *(const bf16x8*)(A + (long)r * K + c);
      }
    }
    if constexpr (BF32) {
      const float* B = (const float*)Bp + zb * sB + (long)n0 * K + kk;
      #pragma unroll
      for (int p = 0; p < 4; ++p) {
        const int r = p * 32 + (tid >> 3);
        const int c = (tid & 7) * 4;
        const float4 v = *(const float4*)(B + (long)r * K + c);
        bf16x4 w;
        w[0] = (__bf16)v.x; w[1] = (__bf16)v.y; w[2] = (__bf16)v.z; w[3] = (__bf16)v.w;
        *(bf16x4*)(&Bs[r * LDSS + c]) = w;
      }
    } else {
      const __bf16* B = (const __bf16*)Bp + zb * sB + (long)n0 * K + kk;
      #pragma unroll
      for (int p = 0; p < 2; ++p) {
        const int r = p * 64 + (tid >> 2);
        const int c = (tid & 3) * 8;
        *(bf16x8*)(&Bs[r * LDSS + c]) = *(const bf16x8*)(B + (long)r * K + c);
      }
    }
    __syncthreads();
    bf16x8 af[4], bq[4];
    #pragma unroll
    for (int i = 0; i < 4; ++i)
      af[i] = *(const bf16x8*)(&As[(wr * 64 + i * 16 + l15) * LDSS + kq]);
    #pragma unroll
    for (int j = 0; j < 4; ++j)
      bq[j] = *(const bf16x8*)(&Bs[(wc * 64 + j * 16 + l15) * LDSS + kq]);
    #pragma unroll
    for (int i = 0; i < 4; ++i)
      #pragma unroll
      for (int j = 0; j < 4; ++j)
        acc[i][j] = __builtin_amdgcn_mfma_f32_16x16x32_bf16(af[i], bq[j], acc[i][j], 0, 0, 0);
    __syncthreads();
  }
  const int rq = (lane >> 4) * 4;
  if constexpr (CBF16) {
    __bf16* C = (__bf16*)Cp + zb * sC;
    #pragma unroll
    for (int i = 0; i < 4; ++i)
      #pragma unroll
      for (int j = 0; j < 4; ++j)
        #pragma unroll
        for (int r = 0; r < 4; ++r)
          C[(long)(m0 + wr * 64 + i * 16 + rq + r) * 2048 +
            (n0 + wc * 64 + j * 16 + l15)] = (__bf16)acc[i][j][r];
  } else {
    float* C = (float*)Cp + zb * sC;
    #pragma unroll
    for (int i = 0; i < 4; ++i)
      #pragma unroll
      for (int j = 0; j < 4; ++j)
        #pragma unroll
        for (int r = 0; r < 4; ++r)
          C[(long)(m0 + wr * 64 + i * 16 + rq + r) * 2048 +
            (n0 + wc * 64 + j * 16 + l15)] = acc[i][j][r];
  }
}

// ---------------------------------------------------------------------------
// fp32 -> bf16 elementwise cast, 8 elems/thread
// ---------------------------------------------------------------------------
__global__ __launch_bounds__(256)
void cast_f32_bf16(const float* __restrict__ src, __bf16* __restrict__ dst)
{
  const long i = ((long)blockIdx.x * 256 + threadIdx.x) * 8;
  const float4 a = *(const float4*)(src + i);
  const float4 b = *(const float4*)(src + i + 4);
  bf16x8 o;
  o[0] = (__bf16)a.x; o[1] = (__bf16)a.y; o[2] = (__bf16)a.z; o[3] = (__bf16)a.w;
  o[4] = (__bf16)b.x; o[5] = (__bf16)b.y; o[6] = (__bf16)b.z; o[7] = (__bf16)b.w;
  *(bf16x8*)(dst + i) = o;
}

// ---------------------------------------------------------------------------
// w_down (E,H,D) fp32 -> wdT (E,D,H) bf16
// ---------------------------------------------------------------------------
__global__ __launch_bounds__(256)
void transpose_cast_wdown(const float* __restrict__ w, __bf16* __restrict__ wt)
{
  __shared__ __bf16 lt[64][72];
  const int e  = blockIdx.z;
  const int hb = blockIdx.y * 64;
  const int db = blockIdx.x * 64;
  const int tid = threadIdx.x;
  const int r  = tid >> 2;
  const int cq = (tid & 3) * 16;

  const float* src = w + (long)e * NH * ND + (long)(hb + r) * ND + db + cq;
  #pragma unroll
  for (int q = 0; q < 4; ++q) {
    const float4 v = *(const float4*)(src + q * 4);
    lt[cq + q * 4 + 0][r] = (__bf16)v.x;
    lt[cq + q * 4 + 1][r] = (__bf16)v.y;
    lt[cq + q * 4 + 2][r] = (__bf16)v.z;
    lt[cq + q * 4 + 3][r] = (__bf16)v.w;
  }
  __syncthreads();
  __bf16* dst = wt + (long)e * ND * NH + (long)(db + r) * NH + hb + cq;
  *(bf16x8*)(dst)     = *(const bf16x8*)(&lt[r][cq]);
  *(bf16x8*)(dst + 8) = *(const bf16x8*)(&lt[r][cq + 8]);
}

// ---------------------------------------------------------------------------
// h = up * silu(gate); ug (E*T, 2H) -> h (E*T, H)
// ---------------------------------------------------------------------------
__global__ __launch_bounds__(256)
void silu_mul(const __bf16* __restrict__ ug, __bf16* __restrict__ h)
{
  const long g  = (long)blockIdx.x * 256 + threadIdx.x;
  const int  c8 = (int)(g & 127) * 8;
  const long row = g >> 7;
  const bf16x8 u  = *(const bf16x8*)(ug + row * 2048 + c8);
  const bf16x8 gt = *(const bf16x8*)(ug + row * 2048 + 1024 + c8);
  bf16x8 o;
  #pragma unroll
  for (int i = 0; i < 8; ++i) {
    const float uu = (float)u[i];
    const float gg = (float)gt[i];
    const float s  = gg / (1.0f + __expf(-gg));
    o[i] = (__bf16)(uu * s);
  }
  *(bf16x8*)(h + row * 1024 + c8) = o;
}

// ---------------------------------------------------------------------------
extern "C" void kernel_launch(void* const* d_in, const int* in_sizes, int n_in,
                              void* d_out, int out_size, void* d_ws, size_t ws_size,
                              hipStream_t stream) {
  const float* x   = (const float*)d_in[0];  // (16384, 2048)
  const float* wug = (const float*)d_in[1];  // (16, 2048, 2048)
  const float* wdn = (const float*)d_in[2];  // (16, 1024, 2048)
  float* out = (float*)d_out;

  const size_t MB = 1024 * 1024;
  char* ws = (char*)d_ws;
  __bf16* wdT = (__bf16*)(ws);             // 64 MiB: (E, D, H) bf16
  __bf16* ug  = (__bf16*)(ws + 64 * MB);   // 64 MiB: (E*T, 2H) bf16
  __bf16* hbf = (__bf16*)(ws + 128 * MB);  // 32 MiB: (E*T, H) bf16

  transpose_cast_wdown<<<dim3(ND / 64, NH / 64, NE), 256, 0, stream>>>(wdn, wdT);

  if (ws_size >= 352 * MB) {
    __bf16* xbf   = (__bf16*)(ws + 160 * MB);  // 64 MiB
    __bf16* wugbf = (__bf16*)(ws + 224 * MB);  // 128 MiB

    cast_f32_bf16<<<16384, 256, 0, stream>>>(x, xbf);        // 33.5M elems
    cast_f32_bf16<<<32768, 256, 0, stream>>>(wug, wugbf);    // 67.1M elems

    gemm_nt_lds<true><<<dim3(2 * NH / 128, NT / 128, NE), 256, 0, stream>>>(
        xbf, wugbf, ug, ND, (long)NT * ND, (long)2 * NH * ND, (long)NT * 2 * NH);

    silu_mul<<<(NE * NT * NH / 8) / 256, 256, 0, stream>>>(ug, hbf);

    gemm_nt_lds<false><<<dim3(ND / 128, NT / 128, NE), 256, 0, stream>>>(
        hbf, wdT, out, NH, (long)NT * NH, (long)ND * NH, (long)NT * ND);
  } else {
    gemm_nt<true, true, true><<<dim3(2 * NH / 128, NT / 128, NE), 256, 0, stream>>>(
        x, wug, ug, ND, (long)NT * ND, (long)2 * NH * ND, (long)NT * 2 * NH);

    silu_mul<<<(NE * NT * NH / 8) / 256, 256, 0, stream>>>(ug, hbf);

    gemm_nt<false, false, false><<<dim3(ND / 128, NT / 128, NE), 256, 0, stream>>>(
        hbf, wdT, out, NH, (long)NT * NH, (long)ND * NH, (long)NT * ND);
  }
}